// Round 5
// baseline (84.393 us; speedup 1.0000x reference)
//
#include <hip/hip_runtime.h>

// PhaseLinear: out[b,o] = sum_c coef[b,c] * (sum_i in[b,i]*W[c,o,i] + bias[c,o])
// All-f32 in / f32 out (round-4 verified), bf16 MFMA internally (absmax 0.031).
// Round 5: NO LDS in main loop. Within a block each W element is used by
// exactly one lane (no intra-block reuse), so LDS staging + per-step barriers
// were pure overhead. Each wave loads A/W fragments direct from global (32B
// contiguous per lane), cvt f32->bf16 in-register, MFMA. Zero K-loop barriers
// -> compiler pipelines loads across the fully-unrolled K loop.

#define BATCH 1024
#define IN_F  512
#define OUT_F 512

constexpr int BM = 32;            // batch rows per block (2 M-frags per wave)
constexpr int BO = 32;            // out features per block (2 waves x 16)
constexpr int BK = 32;            // K per MFMA step
constexpr int KITERS = IN_F / BK; // 16

typedef unsigned short u16;
typedef __bf16 bf16x8 __attribute__((ext_vector_type(8)));
typedef float  f32x4  __attribute__((ext_vector_type(4)));
typedef float  f32x8  __attribute__((ext_vector_type(8)));

__device__ __forceinline__ bf16x8 cvt8(f32x8 v) {   // RNE, v_cvt_pk_bf16_f32
  bf16x8 r;
#pragma unroll
  for (int i = 0; i < 8; ++i) r[i] = (__bf16)v[i];
  return r;
}

__global__ __launch_bounds__(128)
void PhaseLinear_kernel(const float* __restrict__ inp, const float* __restrict__ ph,
                        const float* __restrict__ wts, const float* __restrict__ bia,
                        float* __restrict__ outp) {
  __shared__ float sCoef[BM][4];

  const int tid = threadIdx.x;
  const int wv  = tid >> 6;        // wave 0..1 -> 16-out slice
  const int l   = tid & 63;
  const int o0  = blockIdx.x * BO;
  const int b0  = blockIdx.y * BM;

  // --- spline coefficients (replicates reference tt=[1,t^2,t^3,0] bug) ---
  if (tid < BM) {
    const float PI = 3.14159265358979323846f;
    float p  = ph[b0 + tid];
    float t  = (p < 1.5f * PI) ? (p / (1.5f * PI)) : ((p - 0.5f * PI) / (1.5f * PI));
    float t2 = t * t, t3 = t2 * t;
    sCoef[tid][0] = t3 - 0.5f * t2;        // tt @ (0.5*CATMULL_ROM_BASIS)
    sCoef[tid][1] = 1.0f - 2.5f * t3;
    sCoef[tid][2] = 0.5f * t2 + 2.0f * t3;
    sCoef[tid][3] = -0.5f * t3;
  }
  __syncthreads();                 // only barrier in the kernel

  const int n = l & 15;            // M index (A) / N index (B) / col of C
  const int q = l >> 4;            // k-quad (0..3), k-span q*8..q*8+8

  // per-lane global fragment pointers (32B contiguous each)
  const float* pa0 = inp + (size_t)(b0 + n) * IN_F + q * 8;
  const float* pa1 = pa0 + (size_t)16 * IN_F;
  const float* pw[4];
#pragma unroll
  for (int c = 0; c < 4; ++c)
    pw[c] = wts + ((size_t)c * OUT_F + o0 + wv * 16 + n) * IN_F + q * 8;

  f32x4 acc[2][4];
#pragma unroll
  for (int m = 0; m < 2; ++m)
#pragma unroll
    for (int c = 0; c < 4; ++c) acc[m][c] = (f32x4){0.f, 0.f, 0.f, 0.f};

  // prefetch K-step 0
  f32x8 cur[6];
  cur[0] = *(const f32x8*)(pa0);
  cur[1] = *(const f32x8*)(pa1);
#pragma unroll
  for (int c = 0; c < 4; ++c) cur[2 + c] = *(const f32x8*)(pw[c]);

#pragma unroll
  for (int kk = 0; kk < KITERS; ++kk) {
    // issue next step's loads first (no barrier: vmcnt-scheduled pipeline)
    f32x8 nxt[6];
    if (kk + 1 < KITERS) {
      const int off = (kk + 1) * BK;
      nxt[0] = *(const f32x8*)(pa0 + off);
      nxt[1] = *(const f32x8*)(pa1 + off);
#pragma unroll
      for (int c = 0; c < 4; ++c) nxt[2 + c] = *(const f32x8*)(pw[c] + off);
    }
    bf16x8 a0 = cvt8(cur[0]);
    bf16x8 a1 = cvt8(cur[1]);
#pragma unroll
    for (int c = 0; c < 4; ++c) {
      bf16x8 wf = cvt8(cur[2 + c]);
      acc[0][c] = __builtin_amdgcn_mfma_f32_16x16x32_bf16(a0, wf, acc[0][c], 0, 0, 0);
      acc[1][c] = __builtin_amdgcn_mfma_f32_16x16x32_bf16(a1, wf, acc[1][c], 0, 0, 0);
    }
#pragma unroll
    for (int j = 0; j < 6; ++j) cur[j] = nxt[j];
  }

  // --- epilogue: blend 4 control points + bias, f32 store ---
  // C/D layout (m89/m91 verified): col = l&15, row = (l>>4)*4 + reg
  const int o = o0 + wv * 16 + n;
  float bs[4];
#pragma unroll
  for (int c = 0; c < 4; ++c) bs[c] = bia[c * OUT_F + o];

#pragma unroll
  for (int mf = 0; mf < 2; ++mf) {
#pragma unroll
    for (int r = 0; r < 4; ++r) {
      const int bl = mf * 16 + q * 4 + r;
      float v = 0.f;
#pragma unroll
      for (int c = 0; c < 4; ++c)
        v += sCoef[bl][c] * (acc[mf][c][r] + bs[c]);
      outp[(size_t)(b0 + bl) * OUT_F + o] = v;
    }
  }
}

extern "C" void kernel_launch(void* const* d_in, const int* in_sizes, int n_in,
                              void* d_out, int out_size, void* d_ws, size_t ws_size,
                              hipStream_t stream) {
  const float* inp = (const float*)d_in[0];   // input  (1024, 512) f32
  const float* ph  = (const float*)d_in[1];   // phase  (1024,)     f32
  const float* wts = (const float*)d_in[2];   // weights(4,512,512) f32
  const float* bia = (const float*)d_in[3];   // biases (4,512)     f32
  float* outp = (float*)d_out;                // out    (1024,512)  f32

  dim3 grid(OUT_F / BO, BATCH / BM);          // (16, 32) = 512 blocks, 2/CU
  PhaseLinear_kernel<<<grid, 128, 0, stream>>>(inp, ph, wts, bia, outp);
}